// Round 14
// baseline (134.752 us; speedup 1.0000x reference)
//
#include <hip/hip_runtime.h>
#include <hip/hip_bf16.h>
#include <cstdint>
#include <cstddef>

typedef __bf16 bf16x8 __attribute__((ext_vector_type(8)));
typedef float f32x4 __attribute__((ext_vector_type(4)));
typedef float f32x16 __attribute__((ext_vector_type(16)));
typedef uint32_t u32x4 __attribute__((ext_vector_type(4)));
typedef __hip_bfloat16 bf16h;

__device__ __forceinline__ unsigned short bf16bits(float f) {
  bf16h h = __float2bfloat16(f);
  return __builtin_bit_cast(unsigned short, h);
}

// ---------------- fused prep: hidden cast (blocks 0..4095) + 4 weight transposes + bias ----------------
__global__ __launch_bounds__(256) void prep_all(const float* __restrict__ hs, bf16h* __restrict__ hb,
                                                const float* __restrict__ Wq, const float* __restrict__ Wk,
                                                const float* __restrict__ Wv, const float* __restrict__ Wo,
                                                const float* __restrict__ bq, const float* __restrict__ bk,
                                                const float* __restrict__ bv,
                                                bf16h* __restrict__ WcT, bf16h* __restrict__ WoT,
                                                float* __restrict__ bcat, float qscale) {
  int b = blockIdx.x;
  int tid = threadIdx.x;
  if (b < 4096) {             // ---- cast hidden fp32 -> bf16 (4 elems/thread)
    int i = (b * 256 + tid) * 4;
    float4 v = *reinterpret_cast<const float4*>(hs + i);
    ushort4 o;
    o.x = bf16bits(v.x); o.y = bf16bits(v.y); o.z = bf16bits(v.z); o.w = bf16bits(v.w);
    *reinterpret_cast<ushort4*>(hb + i) = o;
    return;
  }
  b -= 4096;
  if (b >= 3072) {            // ---- bias concat
    int i = (b - 3072) * 256 + tid;
    bcat[i] = (i < 1024) ? bq[i] * qscale : (i < 1536 ? bk[i - 1024] : bv[i - 1536]);
    return;
  }
  // ---- weight transpose+cast
  int tx = tid & 31, ty = tid >> 5;
  const float* src; bf16h* dst; int C, bx, by; float sc = 1.0f;
  if (b < 1024)      { src = Wq; dst = WcT;               C = 1024; bx = b & 31;          by = b >> 5; sc = qscale; }
  else if (b < 1536) { src = Wk; dst = WcT + 1024 * 1024; C = 512;  bx = (b - 1024) & 15; by = (b - 1024) >> 4; }
  else if (b < 2048) { src = Wv; dst = WcT + 1536 * 1024; C = 512;  bx = (b - 1536) & 15; by = (b - 1536) >> 4; }
  else               { src = Wo; dst = WoT;               C = 1024; bx = (b - 2048) & 31; by = (b - 2048) >> 5; }
  __shared__ float tile[32][33];
  int c0 = bx * 32, r0 = by * 32;
  #pragma unroll
  for (int i = 0; i < 32; i += 8)
    tile[ty + i][tx] = src[(size_t)(r0 + ty + i) * C + c0 + tx];
  __syncthreads();
  #pragma unroll
  for (int i = 0; i < 32; i += 8)
    dst[(size_t)(c0 + ty + i) * 1024 + r0 + tx] = __float2bfloat16(tile[tx][ty + i] * sc);
}

// ---------------- QKV GEMM (BM=128 x BN=64, 1024 blocks -> 4 blocks/CU) ----------------
// A hb[4096][1024], BT WcT[2048][1024]. Outputs:
//   cols [0,1024):    qb[row][col] bf16 (row-major, Q pre-scaled via W/bias)
//   cols [1024,1536): kperm: flat = ((g*128+kt)*4+ds)*512 + (hi*32+kl)*8 + e
//   cols [1536,2048): vperm: flat = ((g*128+kt)*4+ks*2+dh)*512 + (hh*32+l31)*8 + e
__global__ __launch_bounds__(256) void gemm_qkv(const bf16h* __restrict__ A, const bf16h* __restrict__ BT,
                                                const float* __restrict__ bias,
                                                bf16h* __restrict__ qb, bf16h* __restrict__ kperm,
                                                bf16h* __restrict__ vperm) {
  __shared__ __align__(16) bf16h As[128 * 64];
  __shared__ __align__(16) bf16h Bs[64 * 64];
  const int tid = threadIdx.x;
  const int lane = tid & 63;
  const int m0 = blockIdx.y * 128, n0 = blockIdx.x * 64;
  const int wid = tid >> 6, wr = wid >> 1, wc = wid & 1;
  const int cl = lane & 15, rg = lane >> 4;
  const int srow = tid >> 3, scol = (tid & 7) * 8;
  const int K = 1024;
  f32x4 acc[4][2] = {};

  for (int k0 = 0; k0 < K; k0 += 64) {
    __syncthreads();
    #pragma unroll
    for (int i = 0; i < 4; ++i) {
      int r = i * 32 + srow;
      __builtin_amdgcn_global_load_lds(
          (__attribute__((address_space(1))) void*)(A + (size_t)(m0 + r) * K + k0 + scol),
          (__attribute__((address_space(3))) void*)(As + i * 2048 + tid * 8), 16, 0, 0);
    }
    #pragma unroll
    for (int i = 0; i < 2; ++i) {
      int s = tid + i * 256;          // 0..511 -> (r, c) of Bs[64][64]
      int r = s >> 3, c = (s & 7) * 8;
      __builtin_amdgcn_global_load_lds(
          (__attribute__((address_space(1))) void*)(BT + (size_t)(n0 + r) * K + k0 + c),
          (__attribute__((address_space(3))) void*)(Bs + s * 8), 16, 0, 0);
    }
    __syncthreads();
    #pragma unroll
    for (int ks = 0; ks < 2; ++ks) {
      bf16x8 af[4], bfr[2];
      #pragma unroll
      for (int mi = 0; mi < 4; ++mi)
        af[mi] = *reinterpret_cast<const bf16x8*>(As + (wr * 64 + mi * 16 + cl) * 64 + ks * 32 + rg * 8);
      #pragma unroll
      for (int ni = 0; ni < 2; ++ni)
        bfr[ni] = *reinterpret_cast<const bf16x8*>(Bs + (wc * 32 + ni * 16 + cl) * 64 + ks * 32 + rg * 8);
      #pragma unroll
      for (int mi = 0; mi < 4; ++mi)
        #pragma unroll
        for (int ni = 0; ni < 2; ++ni)
          acc[mi][ni] = __builtin_amdgcn_mfma_f32_16x16x32_bf16(af[mi], bfr[ni], acc[mi][ni], 0, 0, 0);
    }
  }

  if (n0 < 1024) {          // ---- Q: row-major bf16
    #pragma unroll
    for (int ni = 0; ni < 2; ++ni) {
      int col = n0 + wc * 32 + ni * 16 + cl;
      float bv = bias[col];
      #pragma unroll
      for (int mi = 0; mi < 4; ++mi)
        #pragma unroll
        for (int j = 0; j < 4; ++j) {
          int row = m0 + wr * 64 + mi * 16 + rg * 4 + j;
          qb[(size_t)row * 1024 + col] = __float2bfloat16(acc[mi][ni][j] + bv);
        }
    }
  } else if (n0 < 1536) {   // ---- K permuted
    #pragma unroll
    for (int ni = 0; ni < 2; ++ni) {
      int col = n0 + wc * 32 + ni * 16 + cl;
      float bv = bias[col];
      int cd = col - 1024, gg = cd >> 6, d = cd & 63;
      int ds = d >> 4, hh = (d >> 3) & 1, e = d & 7;
      size_t cbase = (size_t)gg * 262144 + (size_t)ds * 512 + hh * 256 + e;
      #pragma unroll
      for (int mi = 0; mi < 4; ++mi) {
        int row0 = m0 + wr * 64 + mi * 16 + rg * 4;
        #pragma unroll
        for (int j = 0; j < 4; ++j) {
          int k = row0 + j;
          kperm[cbase + (size_t)(k >> 5) * 2048 + (k & 31) * 8] = __float2bfloat16(acc[mi][ni][j] + bv);
        }
      }
    }
  } else {                  // ---- V permuted (4 consecutive k -> ushort4)
    #pragma unroll
    for (int ni = 0; ni < 2; ++ni) {
      int col = n0 + wc * 32 + ni * 16 + cl;
      float bv = bias[col];
      int cd = col - 1536, gg = cd >> 6, d = cd & 63;
      int l31 = d & 31, dh = d >> 5;
      #pragma unroll
      for (int mi = 0; mi < 4; ++mi) {
        int row0 = m0 + wr * 64 + mi * 16 + rg * 4;
        int kt = row0 >> 5, ks = (row0 >> 4) & 1, hh = (row0 >> 3) & 1, e0 = row0 & 7;
        ushort4 o;
        o.x = bf16bits(acc[mi][ni][0] + bv);
        o.y = bf16bits(acc[mi][ni][1] + bv);
        o.z = bf16bits(acc[mi][ni][2] + bv);
        o.w = bf16bits(acc[mi][ni][3] + bv);
        *reinterpret_cast<ushort4*>(vperm + ((size_t)gg * 128 + kt) * 2048 +
                                    (size_t)(ks * 2 + dh) * 512 + (hh * 32 + l31) * 8 + e0) = o;
      }
    }
  }
}

// ---------------- O-projection GEMM: BM=128 x BN=64 tile (512 blocks -> 2 blocks/CU) ----------------
__global__ __launch_bounds__(256) void gemm_bt(const bf16h* __restrict__ A, const bf16h* __restrict__ BT,
                                               const float* __restrict__ bias, float* __restrict__ C,
                                               int M, int N, int K) {
  __shared__ __align__(16) bf16h As[128 * 64];
  __shared__ __align__(16) bf16h Bs[64 * 64];
  const int tid = threadIdx.x;
  const int lane = tid & 63;
  const int m0 = blockIdx.y * 128, n0 = blockIdx.x * 64;
  const int wid = tid >> 6, wr = wid >> 1, wc = wid & 1;
  const int cl = lane & 15, rg = lane >> 4;
  const int srow = tid >> 3, scol = (tid & 7) * 8;
  f32x4 acc[4][2] = {};

  for (int k0 = 0; k0 < K; k0 += 64) {
    __syncthreads();
    #pragma unroll
    for (int i = 0; i < 4; ++i) {
      int r = i * 32 + srow;
      __builtin_amdgcn_global_load_lds(
          (__attribute__((address_space(1))) void*)(A + (size_t)(m0 + r) * K + k0 + scol),
          (__attribute__((address_space(3))) void*)(As + i * 2048 + tid * 8), 16, 0, 0);
    }
    #pragma unroll
    for (int i = 0; i < 2; ++i) {
      int s = tid + i * 256;          // 0..511 -> (r, c) of Bs[64][64]
      int r = s >> 3, c = (s & 7) * 8;
      __builtin_amdgcn_global_load_lds(
          (__attribute__((address_space(1))) void*)(BT + (size_t)(n0 + r) * K + k0 + c),
          (__attribute__((address_space(3))) void*)(Bs + s * 8), 16, 0, 0);
    }
    __syncthreads();
    #pragma unroll
    for (int ks = 0; ks < 2; ++ks) {
      bf16x8 af[4], bfr[2];
      #pragma unroll
      for (int mi = 0; mi < 4; ++mi)
        af[mi] = *reinterpret_cast<const bf16x8*>(As + (wr * 64 + mi * 16 + cl) * 64 + ks * 32 + rg * 8);
      #pragma unroll
      for (int ni = 0; ni < 2; ++ni)
        bfr[ni] = *reinterpret_cast<const bf16x8*>(Bs + (wc * 32 + ni * 16 + cl) * 64 + ks * 32 + rg * 8);
      #pragma unroll
      for (int mi = 0; mi < 4; ++mi)
        #pragma unroll
        for (int ni = 0; ni < 2; ++ni)
          acc[mi][ni] = __builtin_amdgcn_mfma_f32_16x16x32_bf16(af[mi], bfr[ni], acc[mi][ni], 0, 0, 0);
    }
  }
  #pragma unroll
  for (int ni = 0; ni < 2; ++ni) {
    int col = n0 + wc * 32 + ni * 16 + cl;
    float bv = bias[col];
    #pragma unroll
    for (int mi = 0; mi < 4; ++mi)
      #pragma unroll
      for (int j = 0; j < 4; ++j) {
        int row = m0 + wr * 64 + mi * 16 + rg * 4 + j;
        C[(size_t)row * N + col] = acc[mi][ni][j] + bv;
      }
  }
}

// ---------------- flash attention: 4 waves/block, in-block k-split, LDS end-merge ----------------
// QBLK=64/wave (dual-frag), KVBLK=32, permuted coalesced loads; wave w covers k in
// [w*1024, w*1024+1024). Fixed-max softmax => exact merge O = sum_w O_w / sum_w l_w.
// kz: opaque persistent zero f32x16 used as the C operand of each tile's first QK MFMA —
// eliminates the 32 v_mov zero-init per BODY (1024 movs/wave). Pinned via inline asm so the
// compiler cannot rematerialize it as per-tile movs. +16 VGPR (must stay <=128 for 4 waves/SIMD).
__global__ __launch_bounds__(256, 2) void attn_fwd(const bf16h* __restrict__ qb,
                                                   const bf16h* __restrict__ kperm,
                                                   const bf16h* __restrict__ vperm,
                                                   bf16h* __restrict__ ctx) {
  __shared__ float oL[4][64][33];   // [wave][lane][reg], +1 pad -> conflict-free
  __shared__ float lsL[4][64];
  const int t256 = threadIdx.x;
  const int wid = t256 >> 6, lane = t256 & 63;
  const int l31 = lane & 31, hi = lane >> 5;
  const int bid = blockIdx.x;
  const int g = bid & 7, hl = (bid >> 3) & 1, qx = bid >> 4;
  const int h = g * 2 + hl;
  const int q0 = qx * 64;
  const int kt0 = wid * 32;          // this wave's 32 kv-tiles (1024 k's)

  // Q fragments (B-operand of swapped QK)
  bf16x8 qfA[4], qfB[4];
  {
    const bf16h* qrA = qb + (size_t)(q0 + l31) * 1024 + h * 64 + hi * 8;
    #pragma unroll
    for (int ds = 0; ds < 4; ++ds) {
      qfA[ds] = *reinterpret_cast<const bf16x8*>(qrA + ds * 16);
      qfB[ds] = *reinterpret_cast<const bf16x8*>(qrA + (size_t)32 * 1024 + ds * 16);
    }
  }

  const bf16h* kg = kperm + ((size_t)g << 18) + lane * 8;
  const bf16h* vg = vperm + ((size_t)g << 18) + lane * 8;

  // opaque zero C-operand (see kernel comment)
  f32x16 kz;
  #pragma unroll
  for (int i = 0; i < 16; ++i) kz[i] = 0.f;
  asm volatile("" : "+v"(kz));

  f32x16 oA0, oA1, oB0, oB1;
  #pragma unroll
  for (int i = 0; i < 16; ++i) { oA0[i] = 0.f; oA1[i] = 0.f; oB0[i] = 0.f; oB1[i] = 0.f; }
  float lsA = 0.f, lsB = 0.f;

  auto LOAD = [&](bf16x8 (&Kf)[4], bf16x8 (&Vf)[4], int kt) {
    const bf16h* kb = kg + (size_t)kt * 2048;
    const bf16h* vb = vg + (size_t)kt * 2048;
    #pragma unroll
    for (int s = 0; s < 4; ++s) {
      Kf[s] = *reinterpret_cast<const bf16x8*>(kb + s * 512);
      Vf[s] = *reinterpret_cast<const bf16x8*>(vb + s * 512);
    }
  };

  auto build_pa = [&](const f32x16& S, int u) -> bf16x8 {
    uint32_t w0, w1, w2, w3;
    asm("v_cvt_pk_bf16_f32 %0, %1, %2" : "=v"(w0) : "v"(S[8 * u + 0]), "v"(S[8 * u + 1]));
    asm("v_cvt_pk_bf16_f32 %0, %1, %2" : "=v"(w1) : "v"(S[8 * u + 2]), "v"(S[8 * u + 3]));
    asm("v_cvt_pk_bf16_f32 %0, %1, %2" : "=v"(w2) : "v"(S[8 * u + 4]), "v"(S[8 * u + 5]));
    asm("v_cvt_pk_bf16_f32 %0, %1, %2" : "=v"(w3) : "v"(S[8 * u + 6]), "v"(S[8 * u + 7]));
    asm("v_permlane32_swap_b32 %0, %1" : "+v"(w0), "+v"(w2));
    asm("v_permlane32_swap_b32 %0, %1" : "+v"(w1), "+v"(w3));
    u32x4 pw; pw[0] = w0; pw[1] = w1; pw[2] = w2; pw[3] = w3;
    return __builtin_bit_cast(bf16x8, pw);
  };

  auto BODY = [&](const bf16x8 (&Kf)[4], const bf16x8 (&Vf)[4]) {
    __builtin_amdgcn_s_setprio(1);
    f32x16 sA = __builtin_amdgcn_mfma_f32_32x32x16_bf16(Kf[0], qfA[0], kz, 0, 0, 0);
    f32x16 sB = __builtin_amdgcn_mfma_f32_32x32x16_bf16(Kf[0], qfB[0], kz, 0, 0, 0);
    #pragma unroll
    for (int ds = 1; ds < 4; ++ds) {
      sA = __builtin_amdgcn_mfma_f32_32x32x16_bf16(Kf[ds], qfA[ds], sA, 0, 0, 0);
      sB = __builtin_amdgcn_mfma_f32_32x32x16_bf16(Kf[ds], qfB[ds], sB, 0, 0, 0);
    }
    __builtin_amdgcn_s_setprio(0);
    float ra0 = 0.f, ra1 = 0.f, rb0 = 0.f, rb1 = 0.f;
    #pragma unroll
    for (int r = 0; r < 16; r += 4) {
      #pragma unroll
      for (int j = 0; j < 4; ++j) {
        sA[r + j] = __builtin_amdgcn_exp2f(sA[r + j]);
        sB[r + j] = __builtin_amdgcn_exp2f(sB[r + j]);
      }
      ra0 += sA[r] + sA[r + 1]; ra1 += sA[r + 2] + sA[r + 3];
      rb0 += sB[r] + sB[r + 1]; rb1 += sB[r + 2] + sB[r + 3];
    }
    lsA += ra0 + ra1;
    lsB += rb0 + rb1;
    __builtin_amdgcn_s_setprio(1);
    #pragma unroll
    for (int u = 0; u < 2; ++u) {
      bf16x8 paA = build_pa(sA, u);
      bf16x8 paB = build_pa(sB, u);
      oA0 = __builtin_amdgcn_mfma_f32_32x32x16_bf16(Vf[u * 2 + 0], paA, oA0, 0, 0, 0);
      oA1 = __builtin_amdgcn_mfma_f32_32x32x16_bf16(Vf[u * 2 + 1], paA, oA1, 0, 0, 0);
      oB0 = __builtin_amdgcn_mfma_f32_32x32x16_bf16(Vf[u * 2 + 0], paB, oB0, 0, 0, 0);
      oB1 = __builtin_amdgcn_mfma_f32_32x32x16_bf16(Vf[u * 2 + 1], paB, oB1, 0, 0, 0);
    }
    __builtin_amdgcn_s_setprio(0);
  };

  bf16x8 Ka[4], Va[4], Kb[4], Vb[4];
  LOAD(Ka, Va, kt0);
  for (int tt = 0; tt < 32; tt += 2) {
    LOAD(Kb, Vb, kt0 + tt + 1);                          // tt+1 <= 31, in-range
    BODY(Ka, Va);
    int t2 = (tt + 2 <= 31) ? kt0 + tt + 2 : kt0 + 31;   // clamped duplicate prefetch at tail
    LOAD(Ka, Va, t2);
    BODY(Kb, Vb);
  }

  // deferred partner reduction (lane <-> lane^32): exact under fixed-max softmax
  lsA += __shfl_xor(lsA, 32);
  lsB += __shfl_xor(lsB, 32);

  // ---- merge across the 4 waves via LDS, 2 passes (A then B)
  auto merge_pass = [&](const f32x16& x0, const f32x16& x1, float lsv, int qbase) {
    #pragma unroll
    for (int i = 0; i < 16; ++i) {
      oL[wid][lane][i] = x0[i];
      oL[wid][lane][16 + i] = x1[i];
    }
    lsL[wid][lane] = lsv;
    __syncthreads();
    float inv = 1.0f / (lsL[0][lane] + lsL[1][lane] + lsL[2][lane] + lsL[3][lane]);
    const int r0 = 8 * wid;   // this thread merges regs [r0, r0+8) of its lane
    float m[8];
    #pragma unroll
    for (int k = 0; k < 8; ++k)
      m[k] = (oL[0][lane][r0 + k] + oL[1][lane][r0 + k] +
              oL[2][lane][r0 + k] + oL[3][lane][r0 + k]) * inv;
    bf16h* op = ctx + (size_t)(qbase + l31) * 1024 + h * 64;
    #pragma unroll
    for (int half = 0; half < 2; ++half) {
      int r = r0 + half * 4;
      int d0 = 32 * (r >> 4) + 8 * ((r & 15) >> 2) + 4 * hi;
      ushort4 st;
      st.x = bf16bits(m[half * 4 + 0]); st.y = bf16bits(m[half * 4 + 1]);
      st.z = bf16bits(m[half * 4 + 2]); st.w = bf16bits(m[half * 4 + 3]);
      *reinterpret_cast<ushort4*>(op + d0) = st;
    }
    __syncthreads();
  };
  merge_pass(oA0, oA1, lsA, q0);
  merge_pass(oB0, oB1, lsB, q0 + 32);
}

extern "C" void kernel_launch(void* const* d_in, const int* in_sizes, int n_in,
                              void* d_out, int out_size, void* d_ws, size_t ws_size,
                              hipStream_t stream) {
  const float* hs = (const float*)d_in[0];
  const float* Wq = (const float*)d_in[1];
  const float* bq = (const float*)d_in[2];
  const float* Wk = (const float*)d_in[3];
  const float* bk = (const float*)d_in[4];
  const float* Wv = (const float*)d_in[5];
  const float* bv = (const float*)d_in[6];
  const float* Wo = (const float*)d_in[7];
  const float* bo = (const float*)d_in[8];
  float* out = (float*)d_out;

  const float QSCALE = 0.125f * 1.44269504088896f;  // 1/sqrt(64) * log2(e), folded into Wq/bq

  // workspace (30 MB):
  //   [0,8M)   hb (dies after gemm_qkv) -> ctx overlays (attn output)
  //   [8,12M)  WcT (dies after gemm_qkv)
  //   [12,20M) qb
  //   [20,24M) kperm
  //   [24,28M) vperm
  //   [28,30M) WoT; [30M) bcat
  char* ws = (char*)d_ws;
  const size_t MB = 1u << 20;
  bf16h* hb    = (bf16h*)(ws);
  bf16h* ctx   = (bf16h*)(ws);
  bf16h* WcT   = (bf16h*)(ws + 8 * MB);
  bf16h* qb    = (bf16h*)(ws + 12 * MB);
  bf16h* kperm = (bf16h*)(ws + 20 * MB);
  bf16h* vperm = (bf16h*)(ws + 24 * MB);
  bf16h* WoT   = (bf16h*)(ws + 28 * MB);
  float* bcat  = (float*)(ws + 30 * MB);

  prep_all<<<dim3(4096 + 3080), dim3(256), 0, stream>>>(hs, hb, Wq, Wk, Wv, Wo, bq, bk, bv,
                                                        WcT, WoT, bcat, QSCALE);
  gemm_qkv<<<dim3(32, 32), dim3(256), 0, stream>>>(hb, WcT, bcat, qb, kperm, vperm);
  attn_fwd<<<dim3(1024), dim3(256), 0, stream>>>(qb, kperm, vperm, ctx);
  gemm_bt<<<dim3(16, 32), dim3(256), 0, stream>>>(ctx, WoT, bo, out, 4096, 1024, 1024);
}

// Round 15
// 133.586 us; speedup vs baseline: 1.0087x; 1.0087x over previous
//
#include <hip/hip_runtime.h>
#include <hip/hip_bf16.h>
#include <cstdint>
#include <cstddef>

typedef __bf16 bf16x8 __attribute__((ext_vector_type(8)));
typedef float f32x4 __attribute__((ext_vector_type(4)));
typedef float f32x16 __attribute__((ext_vector_type(16)));
typedef uint32_t u32x4 __attribute__((ext_vector_type(4)));
typedef __hip_bfloat16 bf16h;

__device__ __forceinline__ unsigned short bf16bits(float f) {
  bf16h h = __float2bfloat16(f);
  return __builtin_bit_cast(unsigned short, h);
}

// ---------------- fused prep: hidden cast (blocks 0..4095) + 4 weight transposes + bias ----------------
__global__ __launch_bounds__(256) void prep_all(const float* __restrict__ hs, bf16h* __restrict__ hb,
                                                const float* __restrict__ Wq, const float* __restrict__ Wk,
                                                const float* __restrict__ Wv, const float* __restrict__ Wo,
                                                const float* __restrict__ bq, const float* __restrict__ bk,
                                                const float* __restrict__ bv,
                                                bf16h* __restrict__ WcT, bf16h* __restrict__ WoT,
                                                float* __restrict__ bcat, float qscale) {
  int b = blockIdx.x;
  int tid = threadIdx.x;
  if (b < 4096) {             // ---- cast hidden fp32 -> bf16 (4 elems/thread)
    int i = (b * 256 + tid) * 4;
    float4 v = *reinterpret_cast<const float4*>(hs + i);
    ushort4 o;
    o.x = bf16bits(v.x); o.y = bf16bits(v.y); o.z = bf16bits(v.z); o.w = bf16bits(v.w);
    *reinterpret_cast<ushort4*>(hb + i) = o;
    return;
  }
  b -= 4096;
  if (b >= 3072) {            // ---- bias concat
    int i = (b - 3072) * 256 + tid;
    bcat[i] = (i < 1024) ? bq[i] * qscale : (i < 1536 ? bk[i - 1024] : bv[i - 1536]);
    return;
  }
  // ---- weight transpose+cast
  int tx = tid & 31, ty = tid >> 5;
  const float* src; bf16h* dst; int C, bx, by; float sc = 1.0f;
  if (b < 1024)      { src = Wq; dst = WcT;               C = 1024; bx = b & 31;          by = b >> 5; sc = qscale; }
  else if (b < 1536) { src = Wk; dst = WcT + 1024 * 1024; C = 512;  bx = (b - 1024) & 15; by = (b - 1024) >> 4; }
  else if (b < 2048) { src = Wv; dst = WcT + 1536 * 1024; C = 512;  bx = (b - 1536) & 15; by = (b - 1536) >> 4; }
  else               { src = Wo; dst = WoT;               C = 1024; bx = (b - 2048) & 31; by = (b - 2048) >> 5; }
  __shared__ float tile[32][33];
  int c0 = bx * 32, r0 = by * 32;
  #pragma unroll
  for (int i = 0; i < 32; i += 8)
    tile[ty + i][tx] = src[(size_t)(r0 + ty + i) * C + c0 + tx];
  __syncthreads();
  #pragma unroll
  for (int i = 0; i < 32; i += 8)
    dst[(size_t)(c0 + ty + i) * 1024 + r0 + tx] = __float2bfloat16(tile[tx][ty + i] * sc);
}

// ---------------- QKV GEMM (BM=128 x BN=64, 1024 blocks -> 4 blocks/CU) ----------------
// A hb[4096][1024], BT WcT[2048][1024]. Outputs:
//   cols [0,1024):    qb[row][col] bf16 (row-major, Q pre-scaled via W/bias)
//   cols [1024,1536): kperm: flat = ((g*128+kt)*4+ds)*512 + (hi*32+kl)*8 + e
//   cols [1536,2048): vperm: flat = ((g*128+kt)*4+ks*2+dh)*512 + (hh*32+l31)*8 + e
__global__ __launch_bounds__(256) void gemm_qkv(const bf16h* __restrict__ A, const bf16h* __restrict__ BT,
                                                const float* __restrict__ bias,
                                                bf16h* __restrict__ qb, bf16h* __restrict__ kperm,
                                                bf16h* __restrict__ vperm) {
  __shared__ __align__(16) bf16h As[128 * 64];
  __shared__ __align__(16) bf16h Bs[64 * 64];
  const int tid = threadIdx.x;
  const int lane = tid & 63;
  const int m0 = blockIdx.y * 128, n0 = blockIdx.x * 64;
  const int wid = tid >> 6, wr = wid >> 1, wc = wid & 1;
  const int cl = lane & 15, rg = lane >> 4;
  const int srow = tid >> 3, scol = (tid & 7) * 8;
  const int K = 1024;
  f32x4 acc[4][2] = {};

  for (int k0 = 0; k0 < K; k0 += 64) {
    __syncthreads();
    #pragma unroll
    for (int i = 0; i < 4; ++i) {
      int r = i * 32 + srow;
      __builtin_amdgcn_global_load_lds(
          (__attribute__((address_space(1))) void*)(A + (size_t)(m0 + r) * K + k0 + scol),
          (__attribute__((address_space(3))) void*)(As + i * 2048 + tid * 8), 16, 0, 0);
    }
    #pragma unroll
    for (int i = 0; i < 2; ++i) {
      int s = tid + i * 256;          // 0..511 -> (r, c) of Bs[64][64]
      int r = s >> 3, c = (s & 7) * 8;
      __builtin_amdgcn_global_load_lds(
          (__attribute__((address_space(1))) void*)(BT + (size_t)(n0 + r) * K + k0 + c),
          (__attribute__((address_space(3))) void*)(Bs + s * 8), 16, 0, 0);
    }
    __syncthreads();
    #pragma unroll
    for (int ks = 0; ks < 2; ++ks) {
      bf16x8 af[4], bfr[2];
      #pragma unroll
      for (int mi = 0; mi < 4; ++mi)
        af[mi] = *reinterpret_cast<const bf16x8*>(As + (wr * 64 + mi * 16 + cl) * 64 + ks * 32 + rg * 8);
      #pragma unroll
      for (int ni = 0; ni < 2; ++ni)
        bfr[ni] = *reinterpret_cast<const bf16x8*>(Bs + (wc * 32 + ni * 16 + cl) * 64 + ks * 32 + rg * 8);
      #pragma unroll
      for (int mi = 0; mi < 4; ++mi)
        #pragma unroll
        for (int ni = 0; ni < 2; ++ni)
          acc[mi][ni] = __builtin_amdgcn_mfma_f32_16x16x32_bf16(af[mi], bfr[ni], acc[mi][ni], 0, 0, 0);
    }
  }

  if (n0 < 1024) {          // ---- Q: row-major bf16
    #pragma unroll
    for (int ni = 0; ni < 2; ++ni) {
      int col = n0 + wc * 32 + ni * 16 + cl;
      float bv = bias[col];
      #pragma unroll
      for (int mi = 0; mi < 4; ++mi)
        #pragma unroll
        for (int j = 0; j < 4; ++j) {
          int row = m0 + wr * 64 + mi * 16 + rg * 4 + j;
          qb[(size_t)row * 1024 + col] = __float2bfloat16(acc[mi][ni][j] + bv);
        }
    }
  } else if (n0 < 1536) {   // ---- K permuted
    #pragma unroll
    for (int ni = 0; ni < 2; ++ni) {
      int col = n0 + wc * 32 + ni * 16 + cl;
      float bv = bias[col];
      int cd = col - 1024, gg = cd >> 6, d = cd & 63;
      int ds = d >> 4, hh = (d >> 3) & 1, e = d & 7;
      size_t cbase = (size_t)gg * 262144 + (size_t)ds * 512 + hh * 256 + e;
      #pragma unroll
      for (int mi = 0; mi < 4; ++mi) {
        int row0 = m0 + wr * 64 + mi * 16 + rg * 4;
        #pragma unroll
        for (int j = 0; j < 4; ++j) {
          int k = row0 + j;
          kperm[cbase + (size_t)(k >> 5) * 2048 + (k & 31) * 8] = __float2bfloat16(acc[mi][ni][j] + bv);
        }
      }
    }
  } else {                  // ---- V permuted (4 consecutive k -> ushort4)
    #pragma unroll
    for (int ni = 0; ni < 2; ++ni) {
      int col = n0 + wc * 32 + ni * 16 + cl;
      float bv = bias[col];
      int cd = col - 1536, gg = cd >> 6, d = cd & 63;
      int l31 = d & 31, dh = d >> 5;
      #pragma unroll
      for (int mi = 0; mi < 4; ++mi) {
        int row0 = m0 + wr * 64 + mi * 16 + rg * 4;
        int kt = row0 >> 5, ks = (row0 >> 4) & 1, hh = (row0 >> 3) & 1, e0 = row0 & 7;
        ushort4 o;
        o.x = bf16bits(acc[mi][ni][0] + bv);
        o.y = bf16bits(acc[mi][ni][1] + bv);
        o.z = bf16bits(acc[mi][ni][2] + bv);
        o.w = bf16bits(acc[mi][ni][3] + bv);
        *reinterpret_cast<ushort4*>(vperm + ((size_t)gg * 128 + kt) * 2048 +
                                    (size_t)(ks * 2 + dh) * 512 + (hh * 32 + l31) * 8 + e0) = o;
      }
    }
  }
}

// ---------------- O-projection GEMM: BM=128 x BN=64 tile (512 blocks -> 2 blocks/CU) ----------------
__global__ __launch_bounds__(256) void gemm_bt(const bf16h* __restrict__ A, const bf16h* __restrict__ BT,
                                               const float* __restrict__ bias, float* __restrict__ C,
                                               int M, int N, int K) {
  __shared__ __align__(16) bf16h As[128 * 64];
  __shared__ __align__(16) bf16h Bs[64 * 64];
  const int tid = threadIdx.x;
  const int lane = tid & 63;
  const int m0 = blockIdx.y * 128, n0 = blockIdx.x * 64;
  const int wid = tid >> 6, wr = wid >> 1, wc = wid & 1;
  const int cl = lane & 15, rg = lane >> 4;
  const int srow = tid >> 3, scol = (tid & 7) * 8;
  f32x4 acc[4][2] = {};

  for (int k0 = 0; k0 < K; k0 += 64) {
    __syncthreads();
    #pragma unroll
    for (int i = 0; i < 4; ++i) {
      int r = i * 32 + srow;
      __builtin_amdgcn_global_load_lds(
          (__attribute__((address_space(1))) void*)(A + (size_t)(m0 + r) * K + k0 + scol),
          (__attribute__((address_space(3))) void*)(As + i * 2048 + tid * 8), 16, 0, 0);
    }
    #pragma unroll
    for (int i = 0; i < 2; ++i) {
      int s = tid + i * 256;          // 0..511 -> (r, c) of Bs[64][64]
      int r = s >> 3, c = (s & 7) * 8;
      __builtin_amdgcn_global_load_lds(
          (__attribute__((address_space(1))) void*)(BT + (size_t)(n0 + r) * K + k0 + c),
          (__attribute__((address_space(3))) void*)(Bs + s * 8), 16, 0, 0);
    }
    __syncthreads();
    #pragma unroll
    for (int ks = 0; ks < 2; ++ks) {
      bf16x8 af[4], bfr[2];
      #pragma unroll
      for (int mi = 0; mi < 4; ++mi)
        af[mi] = *reinterpret_cast<const bf16x8*>(As + (wr * 64 + mi * 16 + cl) * 64 + ks * 32 + rg * 8);
      #pragma unroll
      for (int ni = 0; ni < 2; ++ni)
        bfr[ni] = *reinterpret_cast<const bf16x8*>(Bs + (wc * 32 + ni * 16 + cl) * 64 + ks * 32 + rg * 8);
      #pragma unroll
      for (int mi = 0; mi < 4; ++mi)
        #pragma unroll
        for (int ni = 0; ni < 2; ++ni)
          acc[mi][ni] = __builtin_amdgcn_mfma_f32_16x16x32_bf16(af[mi], bfr[ni], acc[mi][ni], 0, 0, 0);
    }
  }
  #pragma unroll
  for (int ni = 0; ni < 2; ++ni) {
    int col = n0 + wc * 32 + ni * 16 + cl;
    float bv = bias[col];
    #pragma unroll
    for (int mi = 0; mi < 4; ++mi)
      #pragma unroll
      for (int j = 0; j < 4; ++j) {
        int row = m0 + wr * 64 + mi * 16 + rg * 4 + j;
        C[(size_t)row * N + col] = acc[mi][ni][j] + bv;
      }
  }
}

// ---------------- flash attention: 4 waves/block, in-block k-split, LDS end-merge ----------------
// QBLK=64/wave (dual-frag), KVBLK=32, permuted coalesced loads; wave w covers k in
// [w*1024, w*1024+1024). Fixed-max softmax => exact merge O = sum_w O_w / sum_w l_w.
// (Round-14's zero-C-operand kz trick reverted: neutral-to-negative, kernel is
// dependency-latency-bound, not VALU-issue-bound on the accumulator zero-init.)
__global__ __launch_bounds__(256, 2) void attn_fwd(const bf16h* __restrict__ qb,
                                                   const bf16h* __restrict__ kperm,
                                                   const bf16h* __restrict__ vperm,
                                                   bf16h* __restrict__ ctx) {
  __shared__ float oL[4][64][33];   // [wave][lane][reg], +1 pad -> conflict-free
  __shared__ float lsL[4][64];
  const int t256 = threadIdx.x;
  const int wid = t256 >> 6, lane = t256 & 63;
  const int l31 = lane & 31, hi = lane >> 5;
  const int bid = blockIdx.x;
  const int g = bid & 7, hl = (bid >> 3) & 1, qx = bid >> 4;
  const int h = g * 2 + hl;
  const int q0 = qx * 64;
  const int kt0 = wid * 32;          // this wave's 32 kv-tiles (1024 k's)

  // Q fragments (B-operand of swapped QK)
  bf16x8 qfA[4], qfB[4];
  {
    const bf16h* qrA = qb + (size_t)(q0 + l31) * 1024 + h * 64 + hi * 8;
    #pragma unroll
    for (int ds = 0; ds < 4; ++ds) {
      qfA[ds] = *reinterpret_cast<const bf16x8*>(qrA + ds * 16);
      qfB[ds] = *reinterpret_cast<const bf16x8*>(qrA + (size_t)32 * 1024 + ds * 16);
    }
  }

  const bf16h* kg = kperm + ((size_t)g << 18) + lane * 8;
  const bf16h* vg = vperm + ((size_t)g << 18) + lane * 8;

  f32x16 oA0, oA1, oB0, oB1;
  #pragma unroll
  for (int i = 0; i < 16; ++i) { oA0[i] = 0.f; oA1[i] = 0.f; oB0[i] = 0.f; oB1[i] = 0.f; }
  float lsA = 0.f, lsB = 0.f;

  auto LOAD = [&](bf16x8 (&Kf)[4], bf16x8 (&Vf)[4], int kt) {
    const bf16h* kb = kg + (size_t)kt * 2048;
    const bf16h* vb = vg + (size_t)kt * 2048;
    #pragma unroll
    for (int s = 0; s < 4; ++s) {
      Kf[s] = *reinterpret_cast<const bf16x8*>(kb + s * 512);
      Vf[s] = *reinterpret_cast<const bf16x8*>(vb + s * 512);
    }
  };

  auto build_pa = [&](const f32x16& S, int u) -> bf16x8 {
    uint32_t w0, w1, w2, w3;
    asm("v_cvt_pk_bf16_f32 %0, %1, %2" : "=v"(w0) : "v"(S[8 * u + 0]), "v"(S[8 * u + 1]));
    asm("v_cvt_pk_bf16_f32 %0, %1, %2" : "=v"(w1) : "v"(S[8 * u + 2]), "v"(S[8 * u + 3]));
    asm("v_cvt_pk_bf16_f32 %0, %1, %2" : "=v"(w2) : "v"(S[8 * u + 4]), "v"(S[8 * u + 5]));
    asm("v_cvt_pk_bf16_f32 %0, %1, %2" : "=v"(w3) : "v"(S[8 * u + 6]), "v"(S[8 * u + 7]));
    asm("v_permlane32_swap_b32 %0, %1" : "+v"(w0), "+v"(w2));
    asm("v_permlane32_swap_b32 %0, %1" : "+v"(w1), "+v"(w3));
    u32x4 pw; pw[0] = w0; pw[1] = w1; pw[2] = w2; pw[3] = w3;
    return __builtin_bit_cast(bf16x8, pw);
  };

  auto BODY = [&](const bf16x8 (&Kf)[4], const bf16x8 (&Vf)[4]) {
    f32x16 sA, sB;
    #pragma unroll
    for (int i = 0; i < 16; ++i) { sA[i] = 0.f; sB[i] = 0.f; }
    __builtin_amdgcn_s_setprio(1);
    #pragma unroll
    for (int ds = 0; ds < 4; ++ds) {
      sA = __builtin_amdgcn_mfma_f32_32x32x16_bf16(Kf[ds], qfA[ds], sA, 0, 0, 0);
      sB = __builtin_amdgcn_mfma_f32_32x32x16_bf16(Kf[ds], qfB[ds], sB, 0, 0, 0);
    }
    __builtin_amdgcn_s_setprio(0);
    float ra0 = 0.f, ra1 = 0.f, rb0 = 0.f, rb1 = 0.f;
    #pragma unroll
    for (int r = 0; r < 16; r += 4) {
      #pragma unroll
      for (int j = 0; j < 4; ++j) {
        sA[r + j] = __builtin_amdgcn_exp2f(sA[r + j]);
        sB[r + j] = __builtin_amdgcn_exp2f(sB[r + j]);
      }
      ra0 += sA[r] + sA[r + 1]; ra1 += sA[r + 2] + sA[r + 3];
      rb0 += sB[r] + sB[r + 1]; rb1 += sB[r + 2] + sB[r + 3];
    }
    lsA += ra0 + ra1;
    lsB += rb0 + rb1;
    __builtin_amdgcn_s_setprio(1);
    #pragma unroll
    for (int u = 0; u < 2; ++u) {
      bf16x8 paA = build_pa(sA, u);
      bf16x8 paB = build_pa(sB, u);
      oA0 = __builtin_amdgcn_mfma_f32_32x32x16_bf16(Vf[u * 2 + 0], paA, oA0, 0, 0, 0);
      oA1 = __builtin_amdgcn_mfma_f32_32x32x16_bf16(Vf[u * 2 + 1], paA, oA1, 0, 0, 0);
      oB0 = __builtin_amdgcn_mfma_f32_32x32x16_bf16(Vf[u * 2 + 0], paB, oB0, 0, 0, 0);
      oB1 = __builtin_amdgcn_mfma_f32_32x32x16_bf16(Vf[u * 2 + 1], paB, oB1, 0, 0, 0);
    }
    __builtin_amdgcn_s_setprio(0);
  };

  bf16x8 Ka[4], Va[4], Kb[4], Vb[4];
  LOAD(Ka, Va, kt0);
  for (int tt = 0; tt < 32; tt += 2) {
    LOAD(Kb, Vb, kt0 + tt + 1);                          // tt+1 <= 31, in-range
    BODY(Ka, Va);
    int t2 = (tt + 2 <= 31) ? kt0 + tt + 2 : kt0 + 31;   // clamped duplicate prefetch at tail
    LOAD(Ka, Va, t2);
    BODY(Kb, Vb);
  }

  // deferred partner reduction (lane <-> lane^32): exact under fixed-max softmax
  lsA += __shfl_xor(lsA, 32);
  lsB += __shfl_xor(lsB, 32);

  // ---- merge across the 4 waves via LDS, 2 passes (A then B)
  auto merge_pass = [&](const f32x16& x0, const f32x16& x1, float lsv, int qbase) {
    #pragma unroll
    for (int i = 0; i < 16; ++i) {
      oL[wid][lane][i] = x0[i];
      oL[wid][lane][16 + i] = x1[i];
    }
    lsL[wid][lane] = lsv;
    __syncthreads();
    float inv = 1.0f / (lsL[0][lane] + lsL[1][lane] + lsL[2][lane] + lsL[3][lane]);
    const int r0 = 8 * wid;   // this thread merges regs [r0, r0+8) of its lane
    float m[8];
    #pragma unroll
    for (int k = 0; k < 8; ++k)
      m[k] = (oL[0][lane][r0 + k] + oL[1][lane][r0 + k] +
              oL[2][lane][r0 + k] + oL[3][lane][r0 + k]) * inv;
    bf16h* op = ctx + (size_t)(qbase + l31) * 1024 + h * 64;
    #pragma unroll
    for (int half = 0; half < 2; ++half) {
      int r = r0 + half * 4;
      int d0 = 32 * (r >> 4) + 8 * ((r & 15) >> 2) + 4 * hi;
      ushort4 st;
      st.x = bf16bits(m[half * 4 + 0]); st.y = bf16bits(m[half * 4 + 1]);
      st.z = bf16bits(m[half * 4 + 2]); st.w = bf16bits(m[half * 4 + 3]);
      *reinterpret_cast<ushort4*>(op + d0) = st;
    }
    __syncthreads();
  };
  merge_pass(oA0, oA1, lsA, q0);
  merge_pass(oB0, oB1, lsB, q0 + 32);
}

extern "C" void kernel_launch(void* const* d_in, const int* in_sizes, int n_in,
                              void* d_out, int out_size, void* d_ws, size_t ws_size,
                              hipStream_t stream) {
  const float* hs = (const float*)d_in[0];
  const float* Wq = (const float*)d_in[1];
  const float* bq = (const float*)d_in[2];
  const float* Wk = (const float*)d_in[3];
  const float* bk = (const float*)d_in[4];
  const float* Wv = (const float*)d_in[5];
  const float* bv = (const float*)d_in[6];
  const float* Wo = (const float*)d_in[7];
  const float* bo = (const float*)d_in[8];
  float* out = (float*)d_out;

  const float QSCALE = 0.125f * 1.44269504088896f;  // 1/sqrt(64) * log2(e), folded into Wq/bq

  // workspace (30 MB):
  //   [0,8M)   hb (dies after gemm_qkv) -> ctx overlays (attn output)
  //   [8,12M)  WcT (dies after gemm_qkv)
  //   [12,20M) qb
  //   [20,24M) kperm
  //   [24,28M) vperm
  //   [28,30M) WoT; [30M) bcat
  char* ws = (char*)d_ws;
  const size_t MB = 1u << 20;
  bf16h* hb    = (bf16h*)(ws);
  bf16h* ctx   = (bf16h*)(ws);
  bf16h* WcT   = (bf16h*)(ws + 8 * MB);
  bf16h* qb    = (bf16h*)(ws + 12 * MB);
  bf16h* kperm = (bf16h*)(ws + 20 * MB);
  bf16h* vperm = (bf16h*)(ws + 24 * MB);
  bf16h* WoT   = (bf16h*)(ws + 28 * MB);
  float* bcat  = (float*)(ws + 30 * MB);

  prep_all<<<dim3(4096 + 3080), dim3(256), 0, stream>>>(hs, hb, Wq, Wk, Wv, Wo, bq, bk, bv,
                                                        WcT, WoT, bcat, QSCALE);
  gemm_qkv<<<dim3(32, 32), dim3(256), 0, stream>>>(hb, WcT, bcat, qb, kperm, vperm);
  attn_fwd<<<dim3(1024), dim3(256), 0, stream>>>(qb, kperm, vperm, ctx);
  gemm_bt<<<dim3(16, 32), dim3(256), 0, stream>>>(ctx, WoT, bo, out, 4096, 1024, 1024);
}